// Round 9
// baseline (188.642 us; speedup 1.0000x reference)
//
#include <hip/hip_runtime.h>
#include <math.h>

#define NB 128
#define NR 36
#define NT 128
#define ND 1024
#define WST 64      // w row stride in ws (f16), cols 36..63 = 0

typedef float    f32x4 __attribute__((ext_vector_type(4)));
typedef _Float16 f16x8 __attribute__((ext_vector_type(8)));

__device__ __forceinline__ f16x8 cvt8(const float4 a, const float4 b) {
    f16x8 h;
    h[0] = (_Float16)a.x; h[1] = (_Float16)a.y; h[2] = (_Float16)a.z; h[3] = (_Float16)a.w;
    h[4] = (_Float16)b.x; h[5] = (_Float16)b.y; h[6] = (_Float16)b.z; h[7] = (_Float16)b.w;
    return h;
}
__device__ __forceinline__ float sq8(const float4 a, const float4 b, float s) {
    s = fmaf(a.x,a.x, fmaf(a.y,a.y, fmaf(a.z,a.z, fmaf(a.w,a.w, s))));
    return fmaf(b.x,b.x, fmaf(b.y,b.y, fmaf(b.z,b.z, fmaf(b.w,b.w, s))));
}

// ============ Kernel A: cosine scores + softmax over regions -> w (f16) ============
// B-shaped: no operand LDS, no staging. Wave = (16 tokens x 36 regions, K-quarter),
// operands global->reg->f16->MFMA. LDS only for the 16x48 score combine + norms.
__global__ __launch_bounds__(256, 4)
void scores_softmax(const float* __restrict__ img, const float* __restrict__ cap,
                    _Float16* __restrict__ w_ws) {
    __shared__ float sc_s[16][49];   // score tile (cols 36..47 garbage)
    __shared__ float ni_s[NR];       // img sumsq
    __shared__ float nc_s[16];       // cap sumsq

    const int tid  = threadIdx.x;
    const int phys = blockIdx.x;
    // XCD swizzle (bijective: 1024 = 8*128): XCD x gets contiguous lb chunk
    const int lb = (phys & 7) * 128 + (phys >> 3);
    const int b  = lb >> 3;
    const int tg = lb & 7;
    const int t0 = tg * 16;

    const float* imgB = img + (size_t)b * NR * ND;
    const float* capB = cap + ((size_t)b * NT + t0) * ND;

    const int wv = tid >> 6, lane = tid & 63, ln = lane & 15, hi = lane >> 4;
    const int kq = wv;               // K-quarter [kq*256, kq*256+256)

    for (int i = tid; i < 16 * 49; i += 256) ((float*)sc_s)[i] = 0.f;
    if (tid < NR) ni_s[tid] = 0.f;
    if (tid < 16) nc_s[tid] = 0.f;
    __syncthreads();

    // loop-invariant row pointers (A: cap token=ln; B: img region=nf*16+ln)
    const float* capR  = capB + (size_t)ln * ND + kq * 256 + hi * 8;
    const float* imgR0 = imgB + (size_t)ln * ND + kq * 256 + hi * 8;
    const float* imgR1 = imgB + (size_t)(16 + ln) * ND + kq * 256 + hi * 8;
    const float* imgR2 = imgB + (size_t)(32 + (ln < 4 ? ln : 3)) * ND + kq * 256 + hi * 8;

    f32x4 acc0 = {0.f,0.f,0.f,0.f}, acc1 = acc0, acc2 = acc0;
    float ncp = 0.f, nip0 = 0.f, nip1 = 0.f, nip2 = 0.f;

    #pragma unroll
    for (int s = 0; s < 8; ++s) {
        const float4 c0  = *(const float4*)(capR  + s * 32);
        const float4 c1  = *(const float4*)(capR  + s * 32 + 4);
        const float4 g00 = *(const float4*)(imgR0 + s * 32);
        const float4 g01 = *(const float4*)(imgR0 + s * 32 + 4);
        const float4 g10 = *(const float4*)(imgR1 + s * 32);
        const float4 g11 = *(const float4*)(imgR1 + s * 32 + 4);
        const float4 g20 = *(const float4*)(imgR2 + s * 32);
        const float4 g21 = *(const float4*)(imgR2 + s * 32 + 4);
        ncp  = sq8(c0,  c1,  ncp);
        nip0 = sq8(g00, g01, nip0);
        nip1 = sq8(g10, g11, nip1);
        nip2 = sq8(g20, g21, nip2);
        const f16x8 a  = cvt8(c0,  c1);
        const f16x8 b0 = cvt8(g00, g01);
        const f16x8 b1 = cvt8(g10, g11);
        const f16x8 b2 = cvt8(g20, g21);
        acc0 = __builtin_amdgcn_mfma_f32_16x16x32_f16(a, b0, acc0, 0, 0, 0);
        acc1 = __builtin_amdgcn_mfma_f32_16x16x32_f16(a, b1, acc1, 0, 0, 0);
        acc2 = __builtin_amdgcn_mfma_f32_16x16x32_f16(a, b2, acc2, 0, 0, 0);
    }

    // ---- combine K-quarters (C/D: col=ln -> region, row=hi*4+j -> token) ----
    #pragma unroll
    for (int j = 0; j < 4; ++j) {
        atomicAdd(&sc_s[hi*4 + j][ln],      acc0[j]);
        atomicAdd(&sc_s[hi*4 + j][16 + ln], acc1[j]);
        atomicAdd(&sc_s[hi*4 + j][32 + ln], acc2[j]);
    }
    // norms: reduce over hi (k within quarter), then cross-wave atomic combine
    {
        float s = ncp;  s += __shfl_xor(s, 16, 64); s += __shfl_xor(s, 32, 64);
        if (lane < 16) atomicAdd(&nc_s[ln], s);
        s = nip0;       s += __shfl_xor(s, 16, 64); s += __shfl_xor(s, 32, 64);
        if (lane < 16) atomicAdd(&ni_s[ln], s);
        s = nip1;       s += __shfl_xor(s, 16, 64); s += __shfl_xor(s, 32, 64);
        if (lane < 16) atomicAdd(&ni_s[16 + ln], s);
        s = nip2;       s += __shfl_xor(s, 16, 64); s += __shfl_xor(s, 32, 64);
        if (lane < 4)  atomicAdd(&ni_s[32 + ln], s);
    }
    __syncthreads();   // sc_s, ni_s, nc_s complete

    // ---- softmax over regions, one thread per token; write w (f16, cols 36..63=0) ----
    if (tid < 16) {
        const float nct = sqrtf(nc_s[tid]);
        float v[NR];
        float m = -1e30f;
        #pragma unroll
        for (int r = 0; r < NR; ++r) {
            const float d = fmaxf(sqrtf(ni_s[r]) * nct, 1e-8f);
            v[r] = sc_s[tid][r] / d;
            m = fmaxf(m, v[r]);
        }
        float sum = 0.f;
        #pragma unroll
        for (int r = 0; r < NR; ++r) { v[r] = __expf(v[r] - m); sum += v[r]; }
        const float inv = 1.f / sum;
        _Float16* wO = w_ws + (size_t)(b * NT + t0 + tid) * WST;
        #pragma unroll
        for (int q = 0; q < 8; ++q) {
            f16x8 h;
            #pragma unroll
            for (int j = 0; j < 8; ++j) {
                const int r = q * 8 + j;
                h[j] = (r < NR) ? (_Float16)(v[r] * inv) : (_Float16)0.f;
            }
            *(f16x8*)(wO + q * 8) = h;
        }
    }
}

// ============ Kernel B: out[t][d] = sum_r w[t][r] * img[r][d] via MFMA ============
__global__ __launch_bounds__(256, 4)
void pool_mfma(const float* __restrict__ img, const _Float16* __restrict__ w_ws,
               float* __restrict__ out) {
    const int tid  = threadIdx.x;
    const int phys = blockIdx.x;
    const int lb = (phys & 7) * 256 + (phys >> 3);   // same XCD->batch mapping as kernel A
    const int b  = lb >> 4;
    const int tq = (lb >> 2) & 3;
    const int dq = lb & 3;
    const int t0 = tq * 32;

    const int wv = tid >> 6, lane = tid & 63, ln = lane & 15, hi = lane >> 4;
    const int dw = dq * 256 + wv * 64;               // this wave's d-base (64 wide)

    const float*    imgB = img  + (size_t)b * NR * ND;
    const _Float16* wB   = w_ws + (size_t)(b * NT + t0) * WST;
    float*          outB = out  + ((size_t)(b * NT + t0)) * ND;

    // A-frags (w): A[m=t][k=r]; lane: m = mfrag*16+ln, k = kk*32 + hi*8 + j
    f16x8 afr[2][2];
    #pragma unroll
    for (int mfr = 0; mfr < 2; ++mfr)
        #pragma unroll
        for (int kk = 0; kk < 2; ++kk)
            afr[mfr][kk] = *(const f16x8*)(wB + (mfr * 16 + ln) * WST + kk * 32 + hi * 8);

    f32x4 acc[2][4];
    #pragma unroll
    for (int mfr = 0; mfr < 2; ++mfr)
        #pragma unroll
        for (int nf = 0; nf < 4; ++nf)
            acc[mfr][nf] = (f32x4){0.f, 0.f, 0.f, 0.f};

    #pragma unroll
    for (int nf = 0; nf < 4; ++nf) {
        const int dcol = dw + nf * 16 + ln;
        #pragma unroll
        for (int kk = 0; kk < 2; ++kk) {
            // B-frag (img): B[k=r][n=d]; r >= 36 clamped (w cols are zero there)
            f16x8 bfr;
            #pragma unroll
            for (int j = 0; j < 8; ++j) {
                int r = kk * 32 + hi * 8 + j;
                if (r >= NR) r = NR - 1;             // safe addr; killed by w==0
                bfr[j] = (_Float16)imgB[r * ND + dcol];
            }
            #pragma unroll
            for (int mfr = 0; mfr < 2; ++mfr)
                acc[mfr][nf] = __builtin_amdgcn_mfma_f32_16x16x32_f16(afr[mfr][kk], bfr, acc[mfr][nf], 0, 0, 0);
        }
    }

    // store: D row = mfr*16 + hi*4 + j (token), col = nf*16 + ln (d)
    #pragma unroll
    for (int mfr = 0; mfr < 2; ++mfr)
        #pragma unroll
        for (int nf = 0; nf < 4; ++nf)
            #pragma unroll
            for (int j = 0; j < 4; ++j)
                outB[(size_t)(mfr * 16 + hi * 4 + j) * ND + dw + nf * 16 + ln] = acc[mfr][nf][j];
}

extern "C" void kernel_launch(void* const* d_in, const int* in_sizes, int n_in,
                              void* d_out, int out_size, void* d_ws, size_t ws_size,
                              hipStream_t stream) {
    const float* img = (const float*)d_in[0];   // [B, R, D]
    const float* cap = (const float*)d_in[1];   // [B, T, D]
    float* out = (float*)d_out;                 // [B, T, D]
    _Float16* w_ws = (_Float16*)d_ws;           // [B, T, 64] f16 = 2.0 MB

    scores_softmax<<<NB * 8, 256, 0, stream>>>(img, cap, w_ws);
    pool_mfma<<<NB * 16, 256, 0, stream>>>(img, w_ws, out);
}

// Round 10
// 64.930 us; speedup vs baseline: 2.9053x; 2.9053x over previous
//
#include <hip/hip_runtime.h>
#include <math.h>

#define NB 128
#define NR 36
#define NT 128
#define ND 1024
#define TTA 32      // tokens per scores-block
#define BST 258     // f32 img buf row stride (1032 B; data 1024 B contiguous per row)
#define WST 64      // w row stride in ws (f16), cols 36..63 = 0

typedef float    f32x4 __attribute__((ext_vector_type(4)));
typedef _Float16 f16x8 __attribute__((ext_vector_type(8)));

__device__ __forceinline__ f16x8 cvt8(const float4 a, const float4 b) {
    f16x8 h;
    h[0] = (_Float16)a.x; h[1] = (_Float16)a.y; h[2] = (_Float16)a.z; h[3] = (_Float16)a.w;
    h[4] = (_Float16)b.x; h[5] = (_Float16)b.y; h[6] = (_Float16)b.z; h[7] = (_Float16)b.w;
    return h;
}
__device__ __forceinline__ f16x8 cvt8v(const f32x4 a, const f32x4 b) {
    f16x8 h;
    h[0] = (_Float16)a[0]; h[1] = (_Float16)a[1]; h[2] = (_Float16)a[2]; h[3] = (_Float16)a[3];
    h[4] = (_Float16)b[0]; h[5] = (_Float16)b[1]; h[6] = (_Float16)b[2]; h[7] = (_Float16)b[3];
    return h;
}
__device__ __forceinline__ float sq8(const float4 a, const float4 b, float s) {
    s = fmaf(a.x,a.x, fmaf(a.y,a.y, fmaf(a.z,a.z, fmaf(a.w,a.w, s))));
    return fmaf(b.x,b.x, fmaf(b.y,b.y, fmaf(b.z,b.z, fmaf(b.w,b.w, s))));
}
// async global->LDS, 16 B per lane; dest = lds base + lane*16 (wave-uniform base)
__device__ __forceinline__ void gload_lds16(const float* g, float* l) {
    __builtin_amdgcn_global_load_lds(
        (const __attribute__((address_space(1))) void*)g,
        (__attribute__((address_space(3))) void*)l, 16, 0, 0);
}

// ============ Kernel A: cosine scores + softmax over regions -> w (f16) ============
// r6 structure (best: 39us) with staging swapped to global_load_lds width=16:
// double-buffered f32 img chunks, fire-and-forget stages issued before compute,
// one barrier per chunk; cap streamed global->reg (r6-proven); MFMA algebra r6.
__global__ __launch_bounds__(256, 2)
void scores_softmax(const float* __restrict__ img, const float* __restrict__ cap,
                    _Float16* __restrict__ w_ws) {
    __shared__ __align__(16) float buf[2][NR][BST];   // 74304 B
    __shared__ float sc_s[TTA][49];                   //  6272 B
    __shared__ float ni_s[NR];
    __shared__ float nc_s[TTA];

    const int tid  = threadIdx.x;
    const int phys = blockIdx.x;
    // XCD swizzle: XCD x owns batches [x*16, x*16+16) (matches kernel B)
    const int lb = (phys & 7) * 64 + (phys >> 3);
    const int b  = lb >> 2;
    const int t0 = (lb & 3) * TTA;

    const float* imgB = img + (size_t)b * NR * ND;
    const float* capB = cap + ((size_t)b * NT + t0) * ND;

    const int wv = tid >> 6, lane = tid & 63, ln = lane & 15, hi = lane >> 4;
    const int tg = wv & 1;          // token group (16 tokens)
    const int kq = wv >> 1;         // K-half within each 256-chunk

    for (int i = tid; i < TTA * 49; i += 256) ((float*)sc_s)[i] = 0.f;
    if (tid < TTA) nc_s[tid] = 0.f;

    // ---- stage chunk 0: wave wv owns rows [wv*9, wv*9+9); one gload per row ----
    #pragma unroll
    for (int j = 0; j < 9; ++j) {
        const int row = wv * 9 + j;
        gload_lds16(imgB + (size_t)row * ND + lane * 4, &buf[0][row][0]);
    }

    const float* capR = capB + (size_t)(tg * 16 + ln) * ND + kq * 128 + hi * 8;

    float nip[9] = {0.f,0.f,0.f,0.f,0.f,0.f,0.f,0.f,0.f};
    float ncp = 0.f;
    f32x4 acc0 = {0.f,0.f,0.f,0.f}, acc1 = acc0, acc2 = acc0;

    for (int c = 0; c < 4; ++c) {
        __syncthreads();   // chunk-c stages complete (compiler's vmcnt(0)); buf[(c+1)&1] free
        const float* bc = &buf[c & 1][0][0];

        // issue cap loads for chunk c FIRST (older than stages -> no forced drain)
        float4 pc0 = *(const float4*)(capR + c*256);
        float4 pc1 = *(const float4*)(capR + c*256 + 4);
        float4 pc2 = *(const float4*)(capR + c*256 + 32);
        float4 pc3 = *(const float4*)(capR + c*256 + 36);
        float4 pc4 = *(const float4*)(capR + c*256 + 64);
        float4 pc5 = *(const float4*)(capR + c*256 + 68);
        float4 pc6 = *(const float4*)(capR + c*256 + 96);
        float4 pc7 = *(const float4*)(capR + c*256 + 100);

        // fire-and-forget stage of chunk c+1 into the other buffer
        if (c < 3) {
            #pragma unroll
            for (int j = 0; j < 9; ++j) {
                const int row = wv * 9 + j;
                gload_lds16(imgB + (size_t)row * ND + (c + 1) * 256 + lane * 4,
                            &buf[(c + 1) & 1][row][0]);
            }
        }

        // img norm partials from LDS (this wave's own 9 rows of chunk c)
        #pragma unroll
        for (int j = 0; j < 9; ++j) {
            const f32x4 v = *(const f32x4*)(bc + (size_t)(wv * 9 + j) * BST + lane * 4);
            nip[j] = fmaf(v[0],v[0], fmaf(v[1],v[1], fmaf(v[2],v[2], fmaf(v[3],v[3], nip[j]))));
        }

        // 4 MFMA steps over this wave's K-half of the chunk
        const float* r0 = bc + (size_t)ln * BST;
        const float* r1 = bc + (size_t)(16 + ln) * BST;
        const float* r2 = bc + (size_t)(32 + (ln < 4 ? ln : 3)) * BST;  // clamped, masked later
        #pragma unroll
        for (int s = 0; s < 4; ++s) {
            const float4 ua = (s==0)?pc0:(s==1)?pc2:(s==2)?pc4:pc6;
            const float4 ub = (s==0)?pc1:(s==1)?pc3:(s==2)?pc5:pc7;
            ncp = sq8(ua, ub, ncp);
            const f16x8 a = cvt8(ua, ub);
            const int ko = kq * 128 + s * 32 + hi * 8;
            const f16x8 b0 = cvt8v(*(const f32x4*)(r0 + ko), *(const f32x4*)(r0 + ko + 4));
            const f16x8 b1 = cvt8v(*(const f32x4*)(r1 + ko), *(const f32x4*)(r1 + ko + 4));
            const f16x8 b2 = cvt8v(*(const f32x4*)(r2 + ko), *(const f32x4*)(r2 + ko + 4));
            acc0 = __builtin_amdgcn_mfma_f32_16x16x32_f16(a, b0, acc0, 0, 0, 0);
            acc1 = __builtin_amdgcn_mfma_f32_16x16x32_f16(a, b1, acc1, 0, 0, 0);
            acc2 = __builtin_amdgcn_mfma_f32_16x16x32_f16(a, b2, acc2, 0, 0, 0);
        }
    }

    // ---- combine K-halves (C/D: col=ln -> region, row=hi*4+j -> token) ----
    #pragma unroll
    for (int j = 0; j < 4; ++j) {
        atomicAdd(&sc_s[tg * 16 + hi*4 + j][ln],      acc0[j]);
        atomicAdd(&sc_s[tg * 16 + hi*4 + j][16 + ln], acc1[j]);
        atomicAdd(&sc_s[tg * 16 + hi*4 + j][32 + ln], acc2[j]);
    }
    // img norms: wave-exclusive rows, butterfly reduce, direct write
    #pragma unroll
    for (int j = 0; j < 9; ++j) {
        float s = nip[j];
        #pragma unroll
        for (int off = 32; off; off >>= 1) s += __shfl_xor(s, off, 64);
        if (lane == 0) ni_s[wv * 9 + j] = sqrtf(s);
    }
    // cap norms: lanes {ln, ln+16, ln+32, ln+48} hold k-partials for token tg*16+ln
    {
        float s = ncp;
        s += __shfl_xor(s, 16, 64);
        s += __shfl_xor(s, 32, 64);
        if (lane < 16) atomicAdd(&nc_s[tg * 16 + ln], s);
    }
    __syncthreads();   // sc_s, ni_s, nc_s complete

    // ---- softmax over regions, one thread per token; write w (f16, cols 36..63=0) ----
    if (tid < TTA) {
        const float nct = sqrtf(nc_s[tid]);
        float v[NR];
        float m = -1e30f;
        #pragma unroll
        for (int r = 0; r < NR; ++r) {
            const float d = fmaxf(ni_s[r] * nct, 1e-8f);
            v[r] = sc_s[tid][r] / d;
            m = fmaxf(m, v[r]);
        }
        float sum = 0.f;
        #pragma unroll
        for (int r = 0; r < NR; ++r) { v[r] = __expf(v[r] - m); sum += v[r]; }
        const float inv = 1.f / sum;
        _Float16* wO = w_ws + (size_t)(b * NT + t0 + tid) * WST;
        #pragma unroll
        for (int q = 0; q < 8; ++q) {
            f16x8 h;
            #pragma unroll
            for (int j = 0; j < 8; ++j) {
                const int r = q * 8 + j;
                h[j] = (r < NR) ? (_Float16)(v[r] * inv) : (_Float16)0.f;
            }
            *(f16x8*)(wO + q * 8) = h;
        }
    }
}

// ============ Kernel B: out[t][d] = sum_r w[t][r] * img[r][d] via MFMA ============
__global__ __launch_bounds__(256, 4)
void pool_mfma(const float* __restrict__ img, const _Float16* __restrict__ w_ws,
               float* __restrict__ out) {
    const int tid  = threadIdx.x;
    const int phys = blockIdx.x;
    const int lb = (phys & 7) * 256 + (phys >> 3);   // same XCD->batch mapping as kernel A
    const int b  = lb >> 4;
    const int tq = (lb >> 2) & 3;
    const int dq = lb & 3;
    const int t0 = tq * 32;

    const int wv = tid >> 6, lane = tid & 63, ln = lane & 15, hi = lane >> 4;
    const int dw = dq * 256 + wv * 64;               // this wave's d-base (64 wide)

    const float*    imgB = img  + (size_t)b * NR * ND;
    const _Float16* wB   = w_ws + (size_t)(b * NT + t0) * WST;
    float*          outB = out  + ((size_t)(b * NT + t0)) * ND;

    // A-frags (w): A[m=t][k=r]; lane: m = mfrag*16+ln, k = kk*32 + hi*8 + j
    f16x8 afr[2][2];
    #pragma unroll
    for (int mfr = 0; mfr < 2; ++mfr)
        #pragma unroll
        for (int kk = 0; kk < 2; ++kk)
            afr[mfr][kk] = *(const f16x8*)(wB + (mfr * 16 + ln) * WST + kk * 32 + hi * 8);

    f32x4 acc[2][4];
    #pragma unroll
    for (int mfr = 0; mfr < 2; ++mfr)
        #pragma unroll
        for (int nf = 0; nf < 4; ++nf)
            acc[mfr][nf] = (f32x4){0.f, 0.f, 0.f, 0.f};

    #pragma unroll
    for (int nf = 0; nf < 4; ++nf) {
        const int dcol = dw + nf * 16 + ln;
        #pragma unroll
        for (int kk = 0; kk < 2; ++kk) {
            // B-frag (img): B[k=r][n=d]; r >= 36 clamped (w cols are zero there)
            f16x8 bfr;
            #pragma unroll
            for (int j = 0; j < 8; ++j) {
                int r = kk * 32 + hi * 8 + j;
                if (r >= NR) r = NR - 1;             // safe addr; killed by w==0
                bfr[j] = (_Float16)imgB[r * ND + dcol];
            }
            #pragma unroll
            for (int mfr = 0; mfr < 2; ++mfr)
                acc[mfr][nf] = __builtin_amdgcn_mfma_f32_16x16x32_f16(afr[mfr][kk], bfr, acc[mfr][nf], 0, 0, 0);
        }
    }

    // store: D row = mfr*16 + hi*4 + j (token), col = nf*16 + ln (d)
    #pragma unroll
    for (int mfr = 0; mfr < 2; ++mfr)
        #pragma unroll
        for (int nf = 0; nf < 4; ++nf)
            #pragma unroll
            for (int j = 0; j < 4; ++j)
                outB[(size_t)(mfr * 16 + hi * 4 + j) * ND + dw + nf * 16 + ln] = acc[mfr][nf][j];
}

extern "C" void kernel_launch(void* const* d_in, const int* in_sizes, int n_in,
                              void* d_out, int out_size, void* d_ws, size_t ws_size,
                              hipStream_t stream) {
    const float* img = (const float*)d_in[0];   // [B, R, D]
    const float* cap = (const float*)d_in[1];   // [B, T, D]
    float* out = (float*)d_out;                 // [B, T, D]
    _Float16* w_ws = (_Float16*)d_ws;           // [B, T, 64] f16 = 2.0 MB

    scores_softmax<<<NB * 4, 256, 0, stream>>>(img, cap, w_ws);
    pool_mfma<<<NB * 16, 256, 0, stream>>>(img, w_ws, out);
}

// Round 11
// 49.578 us; speedup vs baseline: 3.8050x; 1.3097x over previous
//
#include <hip/hip_runtime.h>
#include <math.h>

#define NB 128
#define NR 36
#define NT 128
#define ND 1024
#define TTA 32      // tokens per scores-block
#define WST 64      // w row stride in ws (f16), cols 36..63 = 0

typedef float    f32x4 __attribute__((ext_vector_type(4)));
typedef _Float16 f16x8 __attribute__((ext_vector_type(8)));

__device__ __forceinline__ f16x8 cvt8v(const f32x4 a, const f32x4 b) {
    f16x8 h;
    h[0] = (_Float16)a[0]; h[1] = (_Float16)a[1]; h[2] = (_Float16)a[2]; h[3] = (_Float16)a[3];
    h[4] = (_Float16)b[0]; h[5] = (_Float16)b[1]; h[6] = (_Float16)b[2]; h[7] = (_Float16)b[3];
    return h;
}
__device__ __forceinline__ float sq8v(const f32x4 a, const f32x4 b, float s) {
    s = fmaf(a[0],a[0], fmaf(a[1],a[1], fmaf(a[2],a[2], fmaf(a[3],a[3], s))));
    return fmaf(b[0],b[0], fmaf(b[1],b[1], fmaf(b[2],b[2], fmaf(b[3],b[3], s))));
}
// async global->LDS DMA: 16 B/lane, dest = uniform base + lane*16 (linear)
__device__ __forceinline__ void gload_lds16(const void* g, float* l) {
    __builtin_amdgcn_global_load_lds(
        (const __attribute__((address_space(1))) void*)g,
        (__attribute__((address_space(3))) void*)l, 16, 0, 0);
}

// ============ Kernel A: cosine scores + softmax over regions -> w (f16) ============
// ALL staging via fire-and-forget global_load_lds (8-9 KB in flight per wave).
// LDS tile [2][68][128] f32: rows 0..35 img, 36..67 cap(32 tokens); 128-f32 K-chunks.
// XOR-swizzled source (byte ^= (row&7)<<4), linear dest, swizzled reads (rule 21).
__global__ __launch_bounds__(256, 2)
void scores_softmax(const float* __restrict__ img, const float* __restrict__ cap,
                    _Float16* __restrict__ w_ws) {
    __shared__ __align__(16) float buf[2][68][128];   // 69632 B, 512 B rows (no pad!)
    __shared__ float sc_s[TTA][49];                   //  6272 B
    __shared__ float ni_s[NR];                        //  raw sumsq
    __shared__ float nc_s[TTA];                       //  raw sumsq

    const int tid  = threadIdx.x;
    const int phys = blockIdx.x;
    // XCD swizzle: XCD x owns batches [x*16, x*16+16) (matches kernel B)
    const int lb = (phys & 7) * 64 + (phys >> 3);
    const int b  = lb >> 2;
    const int t0 = (lb & 3) * TTA;

    const float* imgB = img + (size_t)b * NR * ND;
    const float* capB = cap + ((size_t)b * NT + t0) * ND;

    const int wv = tid >> 6, lane = tid & 63, ln = lane & 15, hi = lane >> 4;
    const int tg = wv & 1;          // token group (16 tokens)
    const int kq = wv >> 1;         // K-half (64 f32) within each 128-chunk

    for (int i = tid; i < TTA * 49; i += 256) ((float*)sc_s)[i] = 0.f;
    if (tid < NR)  ni_s[tid] = 0.f;
    if (tid < TTA) nc_s[tid] = 0.f;

    // staging ownership: waves 0,1 -> 9 row-pairs; waves 2,3 -> 8 row-pairs (34 total)
    const int p0 = (wv < 2) ? wv * 9 : 18 + (wv - 2) * 8;
    const int np = (wv < 2) ? 9 : 8;
    const int lro = lane >> 5;             // row within pair (0/1)
    const int lu  = (lane & 31) * 16;      // byte unit within 512 B row

    // ---- stage chunk 0 ----
    for (int p = p0; p < p0 + np; ++p) {
        const int row = 2 * p + lro;
        const char* srcrow = (const char*)((2 * p < NR) ? imgB + (size_t)row * ND
                                                        : capB + (size_t)(row - NR) * ND);
        gload_lds16(srcrow + (lu ^ ((row & 7) << 4)), &buf[0][2 * p][0]);
    }
    __syncthreads();   // vmcnt(0) drain = chunk 0 ready; zero-init visible

    f32x4 acc0 = {0.f,0.f,0.f,0.f}, acc1 = acc0, acc2 = acc0;
    float ncp = 0.f, ni0 = 0.f, ni1 = 0.f, ni2 = 0.f;

    const int arow = NR + tg * 16 + ln;                 // cap LDS row
    const int r0 = ln, r1 = 16 + ln, r2 = 32 + (ln < 4 ? ln : 3);  // img rows (r2 clamped)
    const int m_a = (arow & 7) << 4;
    const int m0  = (r0 & 7) << 4, m1 = (r1 & 7) << 4, m2 = (r2 & 7) << 4;

    int cur = 0;
    for (int c = 0; c < 8; ++c) {
        // issue next chunk's DMA first (latency hides under this chunk's compute)
        if (c < 7) {
            const int cb = (c + 1) * 512;
            for (int p = p0; p < p0 + np; ++p) {
                const int row = 2 * p + lro;
                const char* srcrow = (const char*)((2 * p < NR) ? imgB + (size_t)row * ND
                                                                : capB + (size_t)(row - NR) * ND);
                gload_lds16(srcrow + cb + (lu ^ ((row & 7) << 4)), &buf[cur ^ 1][2 * p][0]);
            }
        }
        const char* bb = (const char*)&buf[cur][0][0];
        #pragma unroll
        for (int s = 0; s < 2; ++s) {
            const int kb = kq * 256 + s * 128 + hi * 32;   // byte offset within row
            const f32x4 ca = *(const f32x4*)(bb + arow * 512 + ( kb       ^ m_a));
            const f32x4 cb2= *(const f32x4*)(bb + arow * 512 + ((kb + 16) ^ m_a));
            ncp = sq8v(ca, cb2, ncp);
            const f16x8 a = cvt8v(ca, cb2);
            const f32x4 x0 = *(const f32x4*)(bb + r0 * 512 + ( kb       ^ m0));
            const f32x4 x1 = *(const f32x4*)(bb + r0 * 512 + ((kb + 16) ^ m0));
            const f32x4 y0 = *(const f32x4*)(bb + r1 * 512 + ( kb       ^ m1));
            const f32x4 y1 = *(const f32x4*)(bb + r1 * 512 + ((kb + 16) ^ m1));
            const f32x4 z0 = *(const f32x4*)(bb + r2 * 512 + ( kb       ^ m2));
            const f32x4 z1 = *(const f32x4*)(bb + r2 * 512 + ((kb + 16) ^ m2));
            ni0 = sq8v(x0, x1, ni0); ni1 = sq8v(y0, y1, ni1); ni2 = sq8v(z0, z1, ni2);
            acc0 = __builtin_amdgcn_mfma_f32_16x16x32_f16(a, cvt8v(x0, x1), acc0, 0, 0, 0);
            acc1 = __builtin_amdgcn_mfma_f32_16x16x32_f16(a, cvt8v(y0, y1), acc1, 0, 0, 0);
            acc2 = __builtin_amdgcn_mfma_f32_16x16x32_f16(a, cvt8v(z0, z1), acc2, 0, 0, 0);
        }
        if (c < 7) { __syncthreads(); cur ^= 1; }   // drain DMA (vmcnt0) + buffer handoff
    }

    // ---- combine K-halves (C/D: col=ln -> region, row=hi*4+j -> token; r6-proven) ----
    #pragma unroll
    for (int j = 0; j < 4; ++j) {
        atomicAdd(&sc_s[tg * 16 + hi * 4 + j][ln],      acc0[j]);
        atomicAdd(&sc_s[tg * 16 + hi * 4 + j][16 + ln], acc1[j]);
        atomicAdd(&sc_s[tg * 16 + hi * 4 + j][32 + ln], acc2[j]);
    }
    // img norms: frag reads cover rows x k-half; tg==0 waves contribute (kq 0/1 halves)
    if (tg == 0) {
        float s = ni0; s += __shfl_xor(s, 16, 64); s += __shfl_xor(s, 32, 64);
        if (lane < 16) atomicAdd(&ni_s[ln], s);
        s = ni1;       s += __shfl_xor(s, 16, 64); s += __shfl_xor(s, 32, 64);
        if (lane < 16) atomicAdd(&ni_s[16 + ln], s);
        s = ni2;       s += __shfl_xor(s, 16, 64); s += __shfl_xor(s, 32, 64);
        if (lane < 4)  atomicAdd(&ni_s[32 + ln], s);   // clamped lanes excluded
    }
    // cap norms: token tg*16+ln, k-half kq; both kq waves combine
    {
        float s = ncp;
        s += __shfl_xor(s, 16, 64);
        s += __shfl_xor(s, 32, 64);
        if (lane < 16) atomicAdd(&nc_s[tg * 16 + ln], s);
    }
    __syncthreads();   // sc_s, ni_s, nc_s complete

    // ---- softmax over regions, one thread per token; write w (f16, cols 36..63=0) ----
    if (tid < TTA) {
        const float nct = sqrtf(nc_s[tid]);
        float v[NR];
        float m = -1e30f;
        #pragma unroll
        for (int r = 0; r < NR; ++r) {
            const float d = fmaxf(sqrtf(ni_s[r]) * nct, 1e-8f);
            v[r] = sc_s[tid][r] / d;
            m = fmaxf(m, v[r]);
        }
        float sum = 0.f;
        #pragma unroll
        for (int r = 0; r < NR; ++r) { v[r] = __expf(v[r] - m); sum += v[r]; }
        const float inv = 1.f / sum;
        _Float16* wO = w_ws + (size_t)(b * NT + t0 + tid) * WST;
        #pragma unroll
        for (int q = 0; q < 8; ++q) {
            f16x8 h;
            #pragma unroll
            for (int j = 0; j < 8; ++j) {
                const int r = q * 8 + j;
                h[j] = (r < NR) ? (_Float16)(v[r] * inv) : (_Float16)0.f;
            }
            *(f16x8*)(wO + q * 8) = h;
        }
    }
}

// ============ Kernel B: out[t][d] = sum_r w[t][r] * img[r][d] via MFMA ============
__global__ __launch_bounds__(256, 4)
void pool_mfma(const float* __restrict__ img, const _Float16* __restrict__ w_ws,
               float* __restrict__ out) {
    const int tid  = threadIdx.x;
    const int phys = blockIdx.x;
    const int lb = (phys & 7) * 256 + (phys >> 3);   // same XCD->batch mapping as kernel A
    const int b  = lb >> 4;
    const int tq = (lb >> 2) & 3;
    const int dq = lb & 3;
    const int t0 = tq * 32;

    const int wv = tid >> 6, lane = tid & 63, ln = lane & 15, hi = lane >> 4;
    const int dw = dq * 256 + wv * 64;               // this wave's d-base (64 wide)

    const float*    imgB = img  + (size_t)b * NR * ND;
    const _Float16* wB   = w_ws + (size_t)(b * NT + t0) * WST;
    float*          outB = out  + ((size_t)(b * NT + t0)) * ND;

    // A-frags (w): A[m=t][k=r]; lane: m = mfrag*16+ln, k = kk*32 + hi*8 + j
    f16x8 afr[2][2];
    #pragma unroll
    for (int mfr = 0; mfr < 2; ++mfr)
        #pragma unroll
        for (int kk = 0; kk < 2; ++kk)
            afr[mfr][kk] = *(const f16x8*)(wB + (mfr * 16 + ln) * WST + kk * 32 + hi * 8);

    f32x4 acc[2][4];
    #pragma unroll
    for (int mfr = 0; mfr < 2; ++mfr)
        #pragma unroll
        for (int nf = 0; nf < 4; ++nf)
            acc[mfr][nf] = (f32x4){0.f, 0.f, 0.f, 0.f};

    #pragma unroll
    for (int nf = 0; nf < 4; ++nf) {
        const int dcol = dw + nf * 16 + ln;
        #pragma unroll
        for (int kk = 0; kk < 2; ++kk) {
            // B-frag (img): B[k=r][n=d]; r >= 36 clamped (w cols are zero there)
            f16x8 bfr;
            #pragma unroll
            for (int j = 0; j < 8; ++j) {
                int r = kk * 32 + hi * 8 + j;
                if (r >= NR) r = NR - 1;             // safe addr; killed by w==0
                bfr[j] = (_Float16)imgB[r * ND + dcol];
            }
            #pragma unroll
            for (int mfr = 0; mfr < 2; ++mfr)
                acc[mfr][nf] = __builtin_amdgcn_mfma_f32_16x16x32_f16(afr[mfr][kk], bfr, acc[mfr][nf], 0, 0, 0);
        }
    }

    // store: D row = mfr*16 + hi*4 + j (token), col = nf*16 + ln (d)
    #pragma unroll
    for (int mfr = 0; mfr < 2; ++mfr)
        #pragma unroll
        for (int nf = 0; nf < 4; ++nf)
            #pragma unroll
            for (int j = 0; j < 4; ++j)
                outB[(size_t)(mfr * 16 + hi * 4 + j) * ND + dw + nf * 16 + ln] = acc[mfr][nf][j];
}

extern "C" void kernel_launch(void* const* d_in, const int* in_sizes, int n_in,
                              void* d_out, int out_size, void* d_ws, size_t ws_size,
                              hipStream_t stream) {
    const float* img = (const float*)d_in[0];   // [B, R, D]
    const float* cap = (const float*)d_in[1];   // [B, T, D]
    float* out = (float*)d_out;                 // [B, T, D]
    _Float16* w_ws = (_Float16*)d_ws;           // [B, T, 64] f16 = 2.0 MB

    scores_softmax<<<NB * 4, 256, 0, stream>>>(img, cap, w_ws);
    pool_mfma<<<NB * 16, 256, 0, stream>>>(img, w_ws, out);
}